// Round 15
// baseline (190.529 us; speedup 1.0000x reference)
//
#include <hip/hip_runtime.h>
#include <hip/hip_fp16.h>

#define TPB 256
#define CAP 16384          // slack entries per 256-node bucket (padded fill ~5100)
#define CAPSH 14           // log2(CAP)
#define SC_BLOCKS 256      // scatter blocks
#define MAXE 16            // max edges per scatter thread (E<=TPB*SC_BLOCKS*MAXE)

typedef __attribute__((ext_vector_type(8))) float f32x8;
typedef __attribute__((ext_vector_type(8))) unsigned short u16x8;

// Identity used: dis⊙(x@W) = (dis⊙x)@W and Agg(z@W) = (Agg z)@W, so each
// layer is gather(z) -> mm -> relu, with z = fp16(dis ⊙ activation).
// Buckets: 256 nodes each (dst>>8); bucket b owns pairs/csr[b*CAP..).
// CSR runs padded to a multiple of 8 with index N (zero row).
// meta[v] = { (offset<<8) | nbatches, bitcast(dis) }.
// Layer kernels: 8 threads/node, ushort8 = 16B chunks.
// NEW (R15): nodes are processed in bucket-local DEGREE-SORTED order (perm):
// the 8 groups of a wave run the gather loop in lockstep paying
// max(nbatch) -- sorting makes max ~= mean, killing the ~30% divergence tax.
// CSR untouched -> per-node summation order identical -> bit-identical out.

__device__ __forceinline__ int ld_idx(const void* p, long long i, int is64) {
    return is64 ? (int)((const long long*)p)[i] : ((const int*)p)[i];
}

__device__ __forceinline__ ushort4 f4_to_h4(float4 v) {
    ushort4 r;
    r.x = __half_as_ushort(__float2half_rn(v.x));
    r.y = __half_as_ushort(__float2half_rn(v.y));
    r.z = __half_as_ushort(__float2half_rn(v.z));
    r.w = __half_as_ushort(__float2half_rn(v.w));
    return r;
}

// ---------------------------------------------------------------------------
// SINGLE-PASS scatter: read each edge once, hold packed pairs in registers,
// LDS histogram, one global atomic per non-empty (block,bucket), write out.
// gcur must be zeroed (hipMemsetAsync). Per-block edge-dtype detect.
// ---------------------------------------------------------------------------
__global__ __launch_bounds__(TPB) void p3_scatter(const void* ei, long long E,
                                                  int* gcur, int* pairs) {
    __shared__ int cnt[TPB];
    __shared__ int cur2[TPB];
    __shared__ int s_is64;
    int t = threadIdx.x;
    if (t < 64) {
        const unsigned int* w = (const unsigned int*)ei;
        unsigned long long m = __ballot(w[2 * t + 1] != 0u);
        if (t == 0) s_is64 = (m == 0ull) ? 1 : 0;
    }
    cnt[t] = 0;
    __syncthreads();
    const int is64 = s_is64;
    long long chunk = (E + SC_BLOCKS - 1) / SC_BLOCKS;
    long long s0 = (long long)blockIdx.x * chunk;
    long long s1 = (s0 + chunk < E) ? s0 + chunk : E;

    int pk[MAXE];                                // (src<<8)|(dst&255)
    int bk[MAXE];                                // bucket = dst>>8
    int ne = 0;
    #pragma unroll
    for (int i = 0; i < MAXE; ++i) {
        long long e = s0 + t + (long long)i * TPB;
        if (e < s1) {
            int sv = ld_idx(ei, e, is64);
            int d  = ld_idx(ei, E + e, is64);
            pk[i] = (sv << 8) | (d & 255);
            bk[i] = d >> 8;
            atomicAdd(&cnt[bk[i]], 1);
            ne++;
        }
    }
    __syncthreads();
    if (cnt[t]) cur2[t] = (t << CAPSH) + atomicAdd(&gcur[t], cnt[t]);
    __syncthreads();
    #pragma unroll
    for (int i = 0; i < MAXE; ++i) {
        if (i < ne) {
            int pos = atomicAdd(&cur2[bk[i]], 1);
            pairs[pos] = pk[i];
        }
    }
}

// ---------------------------------------------------------------------------
// One block per bucket: degree count (LDS atomics) -> pad-to-8 256-wide scan
// -> meta, csr scatter via LDS cursors + pad with index N, degree counting
// sort -> perm, then z0 = fp16(dis * x). Block 0 zeroes z0 row N.
// ---------------------------------------------------------------------------
__global__ __launch_bounds__(TPB) void p4_fill(const int* __restrict__ pairs,
                                               const int* __restrict__ gcur,
                                               const float* __restrict__ x,
                                               int2* __restrict__ meta,
                                               int* __restrict__ csr,
                                               int* __restrict__ perm,
                                               ushort4* __restrict__ z0, int N) {
    __shared__ int ldeg[TPB];
    __shared__ int ssc[TPB];
    __shared__ int cur[TPB];
    __shared__ int dh[TPB];
    __shared__ float fdis[TPB];
    int t = threadIdx.x;
    int b = blockIdx.x;
    int base = b << CAPSH;
    int ecnt = gcur[b];                          // real edges in this bucket
    ldeg[t] = 0;
    __syncthreads();
    for (int e = base + t; e < base + ecnt; e += TPB)
        atomicAdd(&ldeg[pairs[e] & 255], 1);
    __syncthreads();
    int dv = ldeg[t];
    int pv = (dv + 7) & ~7;                      // padded to multiple of 8
    ssc[t] = pv;
    __syncthreads();
    for (int off = 1; off < TPB; off <<= 1) {
        int u = 0;
        if (t >= off) u = ssc[t - off];
        __syncthreads();
        ssc[t] += u;
        __syncthreads();
    }
    int o = base + ssc[t] - pv;                  // absolute padded offset
    cur[t] = o;
    float dd = rsqrtf((float)(dv + 1));          // +1 self loop
    fdis[t] = dd;
    int node = (b << 8) + t;
    if (node < N)
        meta[node] = make_int2((o << 8) | (pv >> 3), __float_as_int(dd));
    __syncthreads();
    for (int e = base + t; e < base + ecnt; e += TPB) {
        int p = pairs[e];
        int pos = atomicAdd(&cur[p & 255], 1);
        csr[pos] = p >> 8;
    }
    for (int e = o + dv; e < o + pv; ++e) csr[e] = N;   // pad with zero row

    // --- bucket-local degree counting sort -> perm (invalid nodes: key 0) ---
    int dkey = (node < N) ? ((dv > 255) ? 255 : dv) : 0;
    dh[t] = 0;
    __syncthreads();
    atomicAdd(&dh[dkey], 1);
    __syncthreads();
    int hv = dh[t];
    ssc[t] = hv;
    __syncthreads();
    for (int off = 1; off < TPB; off <<= 1) {
        int u = 0;
        if (t >= off) u = ssc[t - off];
        __syncthreads();
        ssc[t] += u;
        __syncthreads();
    }
    dh[t] = ssc[t] - hv;                         // exclusive scan of degree hist
    __syncthreads();
    int rank = atomicAdd(&dh[dkey], 1);
    perm[(b << 8) + rank] = node;                // node id (may be >= N)

    // z0 conversion: 16 passes, 16 nodes each, coalesced float4 reads.
    int ni = t >> 4, c = t & 15;
    for (int p = 0; p < 16; ++p) {
        int nd = (b << 8) + p * 16 + ni;
        if (nd < N) {
            float dvv = fdis[p * 16 + ni];
            float4 h = ((const float4*)x)[(size_t)nd * 16 + c];
            float4 r = {h.x * dvv, h.y * dvv, h.z * dvv, h.w * dvv};
            z0[(size_t)nd * 16 + c] = f4_to_h4(r);
        }
    }
    if (b == 0 && t < 16) z0[(size_t)N * 16 + t] = make_ushort4(0, 0, 0, 0);
}

// Cooperative gather (fp16 rows as ushort8 = 16 B chunks, PADDED csr):
// 8 lanes batch-load 8 CSR indices in one coalesced read, broadcast via
// __shfl, 8 INDEPENDENT 16B row-chunk loads. Next batch's idx prefetched.
__device__ __forceinline__ f32x8 gather_rows(const u16x8* __restrict__ z8,
                                             const int* __restrict__ csr,
                                             int start, int nbatch, int c,
                                             f32x8 acc) {
    const int base = threadIdx.x & 56;           // 8-lane group base in wave
    int idx = (nbatch > 0) ? csr[start + c] : 0;
    for (int bt = 0; bt < nbatch; ++bt) {
        int nidx = (bt + 1 < nbatch) ? csr[start + (bt + 1) * 8 + c] : 0;
        #pragma unroll
        for (int k = 0; k < 8; ++k) {
            int s = __shfl(idx, base + k);
            u16x8 v = z8[(size_t)s * 8 + c];
            #pragma unroll
            for (int i = 0; i < 8; ++i)
                acc[i] += __half2float(__ushort_as_half(v[i]));
        }
        idx = nidx;
    }
    return acc;
}

// Shfl-based mm for 8-lane groups: lane c holds features 8c..8c+7 of its
// node (f32x8); broadcast via __shfl; lane c accumulates output cols 8c..8c+7.
__device__ __forceinline__ f32x8 shfl_mm8(f32x8 s, const float4* Ws4, int c) {
    const int base = threadIdx.x & 56;
    f32x8 u = {0.f, 0.f, 0.f, 0.f, 0.f, 0.f, 0.f, 0.f};
    #pragma unroll
    for (int q = 0; q < 8; ++q) {
        #pragma unroll
        for (int r = 0; r < 8; ++r) {
            float hv = __shfl(s[r], base + q);   // feature q*8+r
            float4 w0 = Ws4[(q * 8 + r) * 16 + 2 * c];
            float4 w1 = Ws4[(q * 8 + r) * 16 + 2 * c + 1];
            u[0] = fmaf(hv, w0.x, u[0]);
            u[1] = fmaf(hv, w0.y, u[1]);
            u[2] = fmaf(hv, w0.z, u[2]);
            u[3] = fmaf(hv, w0.w, u[3]);
            u[4] = fmaf(hv, w1.x, u[4]);
            u[5] = fmaf(hv, w1.y, u[5]);
            u[6] = fmaf(hv, w1.z, u[6]);
            u[7] = fmaf(hv, w1.w, u[7]);
        }
    }
    return u;
}

__device__ __forceinline__ u16x8 f8_to_h8(f32x8 v) {
    u16x8 r;
    #pragma unroll
    for (int i = 0; i < 8; ++i)
        r[i] = __half_as_ushort(__float2half_rn(v[i]));
    return r;
}

// ---------------------------------------------------------------------------
// Layer: s = z_v + Agg z_u (gather); u = s @ W; zout = fp16(dis*relu(dis*u+b)).
// 32 nodes/block (degree-sorted via perm), 8 threads/node. W in LDS (16 KB).
// ---------------------------------------------------------------------------
__global__ __launch_bounds__(TPB) void layer_mm(const u16x8* __restrict__ z,
                                                const int* __restrict__ csr,
                                                const int2* __restrict__ meta,
                                                const int* __restrict__ perm,
                                                const float* __restrict__ b,
                                                const float* __restrict__ W,
                                                u16x8* __restrict__ zout, int n) {
    __shared__ float Ws[64 * 64];
    int t = threadIdx.x;
    float4* Ws4 = (float4*)Ws;
    const float4* W4g = (const float4*)W;
    #pragma unroll
    for (int i = 0; i < 4; ++i) Ws4[t + i * TPB] = W4g[t + i * TPB];

    if (blockIdx.x == 0 && t < 8) {              // zero row N for next layer
        u16x8 zz = {0, 0, 0, 0, 0, 0, 0, 0};
        zout[(size_t)n * 8 + t] = zz;
    }

    int wave = t >> 6, lane = t & 63;
    int g = lane >> 3, c = lane & 7;
    int node = perm[blockIdx.x * 32 + wave * 8 + g];   // degree-sorted order
    f32x8 s = {0.f, 0.f, 0.f, 0.f, 0.f, 0.f, 0.f, 0.f};
    float dv = 0.f;
    if (node < n) {
        int2 m = meta[node];
        int start = ((unsigned)m.x) >> 8;
        int nbatch = m.x & 255;
        dv = __int_as_float(m.y);
        u16x8 v = z[(size_t)node * 8 + c];       // self-loop term z_v
        #pragma unroll
        for (int i = 0; i < 8; ++i) s[i] = __half2float(__ushort_as_half(v[i]));
        s = gather_rows(z, csr, start, nbatch, c, s);
    }
    __syncthreads();                             // Ws fully staged
    f32x8 u = shfl_mm8(s, Ws4, c);
    if (node < n) {
        float4 b0 = ((const float4*)b)[2 * c];
        float4 b1 = ((const float4*)b)[2 * c + 1];
        f32x8 r;
        r[0] = fmaxf(fmaf(dv, u[0], b0.x), 0.f) * dv;
        r[1] = fmaxf(fmaf(dv, u[1], b0.y), 0.f) * dv;
        r[2] = fmaxf(fmaf(dv, u[2], b0.z), 0.f) * dv;
        r[3] = fmaxf(fmaf(dv, u[3], b0.w), 0.f) * dv;
        r[4] = fmaxf(fmaf(dv, u[4], b1.x), 0.f) * dv;
        r[5] = fmaxf(fmaf(dv, u[5], b1.y), 0.f) * dv;
        r[6] = fmaxf(fmaf(dv, u[6], b1.z), 0.f) * dv;
        r[7] = fmaxf(fmaf(dv, u[7], b1.w), 0.f) * dv;
        zout[(size_t)node * 8 + c] = f8_to_h8(r);    // z_{l+1}
    }
}

// ---------------------------------------------------------------------------
// Final: s = gather(z2); h = relu(dis*(s@W2)+b2); out = h @ linW + linb.
// ---------------------------------------------------------------------------
__global__ __launch_bounds__(TPB) void layer_final(const u16x8* __restrict__ z,
                                                   const int* __restrict__ csr,
                                                   const int2* __restrict__ meta,
                                                   const int* __restrict__ perm,
                                                   const float* __restrict__ b,
                                                   const float* __restrict__ W,
                                                   const float* __restrict__ Wl,
                                                   const float* __restrict__ bl,
                                                   float* __restrict__ out, int n) {
    __shared__ float Ws[64 * 64];
    __shared__ float Wls[64 * 8];
    __shared__ float bls[8];
    int t = threadIdx.x;
    float4* Ws4 = (float4*)Ws;
    const float4* W4g = (const float4*)W;
    #pragma unroll
    for (int i = 0; i < 4; ++i) Ws4[t + i * TPB] = W4g[t + i * TPB];
    if (t < 128) ((float4*)Wls)[t] = ((const float4*)Wl)[t];
    if (t < 8) bls[t] = bl[t];

    int wave = t >> 6, lane = t & 63;
    int g = lane >> 3, c = lane & 7;
    int node = perm[blockIdx.x * 32 + wave * 8 + g];
    f32x8 s = {0.f, 0.f, 0.f, 0.f, 0.f, 0.f, 0.f, 0.f};
    float dv = 0.f;
    if (node < n) {
        int2 m = meta[node];
        int start = ((unsigned)m.x) >> 8;
        int nbatch = m.x & 255;
        dv = __int_as_float(m.y);
        u16x8 v = z[(size_t)node * 8 + c];
        #pragma unroll
        for (int i = 0; i < 8; ++i) s[i] = __half2float(__ushort_as_half(v[i]));
        s = gather_rows(z, csr, start, nbatch, c, s);
    }
    __syncthreads();                             // Ws/Wls/bls staged
    f32x8 u = shfl_mm8(s, Ws4, c);
    float4 b0 = ((const float4*)b)[2 * c];
    float4 b1 = ((const float4*)b)[2 * c + 1];
    f32x8 h;
    h[0] = fmaxf(fmaf(dv, u[0], b0.x), 0.f);
    h[1] = fmaxf(fmaf(dv, u[1], b0.y), 0.f);
    h[2] = fmaxf(fmaf(dv, u[2], b0.z), 0.f);
    h[3] = fmaxf(fmaf(dv, u[3], b0.w), 0.f);
    h[4] = fmaxf(fmaf(dv, u[4], b1.x), 0.f);
    h[5] = fmaxf(fmaf(dv, u[5], b1.y), 0.f);
    h[6] = fmaxf(fmaf(dv, u[6], b1.z), 0.f);
    h[7] = fmaxf(fmaf(dv, u[7], b1.w), 0.f);

    // second mm (64 -> 8): lane c computes output col c.
    const int base = threadIdx.x & 56;
    float acc = bls[c];
    #pragma unroll
    for (int q = 0; q < 8; ++q) {
        #pragma unroll
        for (int r = 0; r < 8; ++r) {
            float hv = __shfl(h[r], base + q);   // feature q*8+r
            acc = fmaf(hv, Wls[(q * 8 + r) * 8 + c], acc);
        }
    }
    if (node < n) out[(size_t)node * 8 + c] = acc;
}

extern "C" void kernel_launch(void* const* d_in, const int* in_sizes, int n_in,
                              void* d_out, int out_size, void* d_ws, size_t ws_size,
                              hipStream_t stream) {
    const float* x  = (const float*)d_in[0];
    const void*  ei = d_in[1];
    const float* W0 = (const float*)d_in[2];
    const float* b0 = (const float*)d_in[3];
    const float* W1 = (const float*)d_in[4];
    const float* b1 = (const float*)d_in[5];
    const float* W2 = (const float*)d_in[6];
    const float* b2 = (const float*)d_in[7];
    const float* Wl = (const float*)d_in[8];
    const float* bl = (const float*)d_in[9];

    const long long E = in_sizes[1] / 2;                 // 800000
    const int dh = in_sizes[3];                          // 64
    const int din = in_sizes[2] / dh;                    // 64
    const int N = in_sizes[0] / din;                     // 50000
    const int nb = (N + 255) >> 8;                       // 196 buckets

    // Workspace carve (256-aligned): ~39 MB total
    char* ws = (char*)d_ws;
    size_t off = 0;
    auto alloc = [&](size_t bytes) -> char* {
        char* r = ws + off;
        off += (bytes + 255) & ~(size_t)255;
        return r;
    };
    int*   gcur    = (int*)  alloc(1024);
    int2*  meta    = (int2*) alloc((size_t)N * 8);
    int*   perm    = (int*)  alloc((size_t)nb * 256 * 4);       // 200 KB
    int*   pairs   = (int*)  alloc((size_t)nb * CAP * 4);       // 12.8 MB
    int*   csr     = (int*)  alloc((size_t)nb * CAP * 4);       // 12.8 MB
    u16x8* zbA     = (u16x8*)alloc((size_t)(N + 1) * 64 * 2);   // fp16 rows (+zero row)
    u16x8* zbB     = (u16x8*)alloc((size_t)(N + 1) * 64 * 2);

    // --- preprocessing ---
    hipMemsetAsync(gcur, 0, 256 * sizeof(int), stream);
    p3_scatter<<<SC_BLOCKS, TPB, 0, stream>>>(ei, E, gcur, pairs);
    p4_fill<<<nb, TPB, 0, stream>>>(pairs, gcur, x, meta, csr, perm,
                                    (ushort4*)zbA, N);

    // --- 3 layers over ALL perm slots (invalid ids filtered by node<n) ---
    const int gL = nb * 8;                               // (nb*256)/32 = 1568
    layer_mm<<<gL, TPB, 0, stream>>>(zbA, csr, meta, perm, b0, W0, zbB, N);
    layer_mm<<<gL, TPB, 0, stream>>>(zbB, csr, meta, perm, b1, W1, zbA, N);
    layer_final<<<gL, TPB, 0, stream>>>(zbA, csr, meta, perm, b2, W2, Wl, bl,
                                        (float*)d_out, N);
}

// Round 16
// 186.866 us; speedup vs baseline: 1.0196x; 1.0196x over previous
//
#include <hip/hip_runtime.h>
#include <hip/hip_fp16.h>

#define TPB 256
#define CAP 16384          // slack entries per 256-node bucket (padded fill ~5100)
#define CAPSH 14           // log2(CAP)
#define SC_BLOCKS 256      // scatter blocks
#define MAXE 16            // max edges per scatter thread (E<=TPB*SC_BLOCKS*MAXE)

typedef __attribute__((ext_vector_type(8))) float f32x8;
typedef __attribute__((ext_vector_type(8))) unsigned short u16x8;

// Identity used: dis⊙(x@W) = (dis⊙x)@W and Agg(z@W) = (Agg z)@W, so each
// layer is gather(z) -> mm -> relu, with z = fp16(dis ⊙ activation).
// Buckets: 256 nodes each (dst>>8); bucket b owns pairs/csr[b*CAP..).
// CSR runs padded to a multiple of 8 with index N (zero row).
// meta[v] = { (offset<<8) | nbatches, bitcast(dis) }.
// Layer kernels: 8 threads/node, ushort8 = 16B chunks.
// R16: CHUNK-OF-32 local degree sort (perm). R15's bucket-global sort lost
// its divergence win to block-tail imbalance + locality loss; sorting only
// within each block's own 32-node chunk keeps per-block work and the 4KB
// locality window identical to R14 while equalizing nbatch across the 8
// lockstep groups of each wave. Summation order untouched -> bit-identical.

__device__ __forceinline__ int ld_idx(const void* p, long long i, int is64) {
    return is64 ? (int)((const long long*)p)[i] : ((const int*)p)[i];
}

__device__ __forceinline__ ushort4 f4_to_h4(float4 v) {
    ushort4 r;
    r.x = __half_as_ushort(__float2half_rn(v.x));
    r.y = __half_as_ushort(__float2half_rn(v.y));
    r.z = __half_as_ushort(__float2half_rn(v.z));
    r.w = __half_as_ushort(__float2half_rn(v.w));
    return r;
}

// ---------------------------------------------------------------------------
// SINGLE-PASS scatter: read each edge once, hold packed pairs in registers,
// LDS histogram, one global atomic per non-empty (block,bucket), write out.
// gcur must be zeroed (hipMemsetAsync). Per-block edge-dtype detect.
// ---------------------------------------------------------------------------
__global__ __launch_bounds__(TPB) void p3_scatter(const void* ei, long long E,
                                                  int* gcur, int* pairs) {
    __shared__ int cnt[TPB];
    __shared__ int cur2[TPB];
    __shared__ int s_is64;
    int t = threadIdx.x;
    if (t < 64) {
        const unsigned int* w = (const unsigned int*)ei;
        unsigned long long m = __ballot(w[2 * t + 1] != 0u);
        if (t == 0) s_is64 = (m == 0ull) ? 1 : 0;
    }
    cnt[t] = 0;
    __syncthreads();
    const int is64 = s_is64;
    long long chunk = (E + SC_BLOCKS - 1) / SC_BLOCKS;
    long long s0 = (long long)blockIdx.x * chunk;
    long long s1 = (s0 + chunk < E) ? s0 + chunk : E;

    int pk[MAXE];                                // (src<<8)|(dst&255)
    int bk[MAXE];                                // bucket = dst>>8
    int ne = 0;
    #pragma unroll
    for (int i = 0; i < MAXE; ++i) {
        long long e = s0 + t + (long long)i * TPB;
        if (e < s1) {
            int sv = ld_idx(ei, e, is64);
            int d  = ld_idx(ei, E + e, is64);
            pk[i] = (sv << 8) | (d & 255);
            bk[i] = d >> 8;
            atomicAdd(&cnt[bk[i]], 1);
            ne++;
        }
    }
    __syncthreads();
    if (cnt[t]) cur2[t] = (t << CAPSH) + atomicAdd(&gcur[t], cnt[t]);
    __syncthreads();
    #pragma unroll
    for (int i = 0; i < MAXE; ++i) {
        if (i < ne) {
            int pos = atomicAdd(&cur2[bk[i]], 1);
            pairs[pos] = pk[i];
        }
    }
}

// ---------------------------------------------------------------------------
// One block per bucket: degree count (LDS atomics) -> pad-to-8 256-wide scan
// -> meta, csr scatter via LDS cursors + pad with index N, chunk-of-32 local
// degree rank -> perm, then z0 = fp16(dis * x). Block 0 zeroes z0 row N.
// ---------------------------------------------------------------------------
__global__ __launch_bounds__(TPB) void p4_fill(const int* __restrict__ pairs,
                                               const int* __restrict__ gcur,
                                               const float* __restrict__ x,
                                               int2* __restrict__ meta,
                                               int* __restrict__ csr,
                                               int* __restrict__ perm,
                                               ushort4* __restrict__ z0, int N) {
    __shared__ int ldeg[TPB];
    __shared__ int ssc[TPB];
    __shared__ int cur[TPB];
    __shared__ float fdis[TPB];
    int t = threadIdx.x;
    int b = blockIdx.x;
    int base = b << CAPSH;
    int ecnt = gcur[b];                          // real edges in this bucket
    ldeg[t] = 0;
    __syncthreads();
    for (int e = base + t; e < base + ecnt; e += TPB)
        atomicAdd(&ldeg[pairs[e] & 255], 1);
    __syncthreads();
    int dv = ldeg[t];
    int pv = (dv + 7) & ~7;                      // padded to multiple of 8
    ssc[t] = pv;
    __syncthreads();
    for (int off = 1; off < TPB; off <<= 1) {
        int u = 0;
        if (t >= off) u = ssc[t - off];
        __syncthreads();
        ssc[t] += u;
        __syncthreads();
    }
    int o = base + ssc[t] - pv;                  // absolute padded offset
    cur[t] = o;
    float dd = rsqrtf((float)(dv + 1));          // +1 self loop
    fdis[t] = dd;
    int node = (b << 8) + t;
    if (node < N)
        meta[node] = make_int2((o << 8) | (pv >> 3), __float_as_int(dd));
    __syncthreads();
    for (int e = base + t; e < base + ecnt; e += TPB) {
        int p = pairs[e];
        int pos = atomicAdd(&cur[p & 255], 1);
        csr[pos] = p >> 8;
    }
    for (int e = o + dv; e < o + pv; ++e) csr[e] = N;   // pad with zero row

    // --- chunk-of-32 local degree rank -> perm ---
    // ldeg[] still holds this bucket's degrees (finalized above). Each thread
    // ranks its node within its own 32-node chunk by (degree, index): the 8
    // groups of a wave then process degree-adjacent nodes (lockstep max ~=
    // mean) while each block keeps exactly its R14 node set + locality.
    {
        int cbase = t & ~31;                     // chunk base (8 chunks of 32)
        int rank = 0;
        for (int j = 0; j < 32; ++j) {
            int dj = ldeg[cbase + j];
            if (dj < dv || (dj == dv && (cbase + j) < t)) rank++;
        }
        perm[(b << 8) + cbase + rank] = node;    // node id (may be >= N)
    }

    // z0 conversion: 16 passes, 16 nodes each, coalesced float4 reads.
    int ni = t >> 4, c = t & 15;
    for (int p = 0; p < 16; ++p) {
        int nd = (b << 8) + p * 16 + ni;
        if (nd < N) {
            float dvv = fdis[p * 16 + ni];
            float4 h = ((const float4*)x)[(size_t)nd * 16 + c];
            float4 r = {h.x * dvv, h.y * dvv, h.z * dvv, h.w * dvv};
            z0[(size_t)nd * 16 + c] = f4_to_h4(r);
        }
    }
    if (b == 0 && t < 16) z0[(size_t)N * 16 + t] = make_ushort4(0, 0, 0, 0);
}

// Cooperative gather (fp16 rows as ushort8 = 16 B chunks, PADDED csr):
// 8 lanes batch-load 8 CSR indices in one coalesced read, broadcast via
// __shfl, 8 INDEPENDENT 16B row-chunk loads. Next batch's idx prefetched.
__device__ __forceinline__ f32x8 gather_rows(const u16x8* __restrict__ z8,
                                             const int* __restrict__ csr,
                                             int start, int nbatch, int c,
                                             f32x8 acc) {
    const int base = threadIdx.x & 56;           // 8-lane group base in wave
    int idx = (nbatch > 0) ? csr[start + c] : 0;
    for (int bt = 0; bt < nbatch; ++bt) {
        int nidx = (bt + 1 < nbatch) ? csr[start + (bt + 1) * 8 + c] : 0;
        #pragma unroll
        for (int k = 0; k < 8; ++k) {
            int s = __shfl(idx, base + k);
            u16x8 v = z8[(size_t)s * 8 + c];
            #pragma unroll
            for (int i = 0; i < 8; ++i)
                acc[i] += __half2float(__ushort_as_half(v[i]));
        }
        idx = nidx;
    }
    return acc;
}

// Shfl-based mm for 8-lane groups: lane c holds features 8c..8c+7 of its
// node (f32x8); broadcast via __shfl; lane c accumulates output cols 8c..8c+7.
__device__ __forceinline__ f32x8 shfl_mm8(f32x8 s, const float4* Ws4, int c) {
    const int base = threadIdx.x & 56;
    f32x8 u = {0.f, 0.f, 0.f, 0.f, 0.f, 0.f, 0.f, 0.f};
    #pragma unroll
    for (int q = 0; q < 8; ++q) {
        #pragma unroll
        for (int r = 0; r < 8; ++r) {
            float hv = __shfl(s[r], base + q);   // feature q*8+r
            float4 w0 = Ws4[(q * 8 + r) * 16 + 2 * c];
            float4 w1 = Ws4[(q * 8 + r) * 16 + 2 * c + 1];
            u[0] = fmaf(hv, w0.x, u[0]);
            u[1] = fmaf(hv, w0.y, u[1]);
            u[2] = fmaf(hv, w0.z, u[2]);
            u[3] = fmaf(hv, w0.w, u[3]);
            u[4] = fmaf(hv, w1.x, u[4]);
            u[5] = fmaf(hv, w1.y, u[5]);
            u[6] = fmaf(hv, w1.z, u[6]);
            u[7] = fmaf(hv, w1.w, u[7]);
        }
    }
    return u;
}

__device__ __forceinline__ u16x8 f8_to_h8(f32x8 v) {
    u16x8 r;
    #pragma unroll
    for (int i = 0; i < 8; ++i)
        r[i] = __half_as_ushort(__float2half_rn(v[i]));
    return r;
}

// ---------------------------------------------------------------------------
// Layer: s = z_v + Agg z_u (gather); u = s @ W; zout = fp16(dis*relu(dis*u+b)).
// 32 nodes/block (chunk-degree-sorted via perm), 8 threads/node. W in LDS.
// ---------------------------------------------------------------------------
__global__ __launch_bounds__(TPB) void layer_mm(const u16x8* __restrict__ z,
                                                const int* __restrict__ csr,
                                                const int2* __restrict__ meta,
                                                const int* __restrict__ perm,
                                                const float* __restrict__ b,
                                                const float* __restrict__ W,
                                                u16x8* __restrict__ zout, int n) {
    __shared__ float Ws[64 * 64];
    int t = threadIdx.x;
    float4* Ws4 = (float4*)Ws;
    const float4* W4g = (const float4*)W;
    #pragma unroll
    for (int i = 0; i < 4; ++i) Ws4[t + i * TPB] = W4g[t + i * TPB];

    if (blockIdx.x == 0 && t < 8) {              // zero row N for next layer
        u16x8 zz = {0, 0, 0, 0, 0, 0, 0, 0};
        zout[(size_t)n * 8 + t] = zz;
    }

    int wave = t >> 6, lane = t & 63;
    int g = lane >> 3, c = lane & 7;
    int node = perm[blockIdx.x * 32 + wave * 8 + g];   // chunk-sorted order
    f32x8 s = {0.f, 0.f, 0.f, 0.f, 0.f, 0.f, 0.f, 0.f};
    float dv = 0.f;
    if (node < n) {
        int2 m = meta[node];
        int start = ((unsigned)m.x) >> 8;
        int nbatch = m.x & 255;
        dv = __int_as_float(m.y);
        u16x8 v = z[(size_t)node * 8 + c];       // self-loop term z_v
        #pragma unroll
        for (int i = 0; i < 8; ++i) s[i] = __half2float(__ushort_as_half(v[i]));
        s = gather_rows(z, csr, start, nbatch, c, s);
    }
    __syncthreads();                             // Ws fully staged
    f32x8 u = shfl_mm8(s, Ws4, c);
    if (node < n) {
        float4 b0 = ((const float4*)b)[2 * c];
        float4 b1 = ((const float4*)b)[2 * c + 1];
        f32x8 r;
        r[0] = fmaxf(fmaf(dv, u[0], b0.x), 0.f) * dv;
        r[1] = fmaxf(fmaf(dv, u[1], b0.y), 0.f) * dv;
        r[2] = fmaxf(fmaf(dv, u[2], b0.z), 0.f) * dv;
        r[3] = fmaxf(fmaf(dv, u[3], b0.w), 0.f) * dv;
        r[4] = fmaxf(fmaf(dv, u[4], b1.x), 0.f) * dv;
        r[5] = fmaxf(fmaf(dv, u[5], b1.y), 0.f) * dv;
        r[6] = fmaxf(fmaf(dv, u[6], b1.z), 0.f) * dv;
        r[7] = fmaxf(fmaf(dv, u[7], b1.w), 0.f) * dv;
        zout[(size_t)node * 8 + c] = f8_to_h8(r);    // z_{l+1}
    }
}

// ---------------------------------------------------------------------------
// Final: s = gather(z2); h = relu(dis*(s@W2)+b2); out = h @ linW + linb.
// ---------------------------------------------------------------------------
__global__ __launch_bounds__(TPB) void layer_final(const u16x8* __restrict__ z,
                                                   const int* __restrict__ csr,
                                                   const int2* __restrict__ meta,
                                                   const int* __restrict__ perm,
                                                   const float* __restrict__ b,
                                                   const float* __restrict__ W,
                                                   const float* __restrict__ Wl,
                                                   const float* __restrict__ bl,
                                                   float* __restrict__ out, int n) {
    __shared__ float Ws[64 * 64];
    __shared__ float Wls[64 * 8];
    __shared__ float bls[8];
    int t = threadIdx.x;
    float4* Ws4 = (float4*)Ws;
    const float4* W4g = (const float4*)W;
    #pragma unroll
    for (int i = 0; i < 4; ++i) Ws4[t + i * TPB] = W4g[t + i * TPB];
    if (t < 128) ((float4*)Wls)[t] = ((const float4*)Wl)[t];
    if (t < 8) bls[t] = bl[t];

    int wave = t >> 6, lane = t & 63;
    int g = lane >> 3, c = lane & 7;
    int node = perm[blockIdx.x * 32 + wave * 8 + g];
    f32x8 s = {0.f, 0.f, 0.f, 0.f, 0.f, 0.f, 0.f, 0.f};
    float dv = 0.f;
    if (node < n) {
        int2 m = meta[node];
        int start = ((unsigned)m.x) >> 8;
        int nbatch = m.x & 255;
        dv = __int_as_float(m.y);
        u16x8 v = z[(size_t)node * 8 + c];
        #pragma unroll
        for (int i = 0; i < 8; ++i) s[i] = __half2float(__ushort_as_half(v[i]));
        s = gather_rows(z, csr, start, nbatch, c, s);
    }
    __syncthreads();                             // Ws/Wls/bls staged
    f32x8 u = shfl_mm8(s, Ws4, c);
    float4 b0 = ((const float4*)b)[2 * c];
    float4 b1 = ((const float4*)b)[2 * c + 1];
    f32x8 h;
    h[0] = fmaxf(fmaf(dv, u[0], b0.x), 0.f);
    h[1] = fmaxf(fmaf(dv, u[1], b0.y), 0.f);
    h[2] = fmaxf(fmaf(dv, u[2], b0.z), 0.f);
    h[3] = fmaxf(fmaf(dv, u[3], b0.w), 0.f);
    h[4] = fmaxf(fmaf(dv, u[4], b1.x), 0.f);
    h[5] = fmaxf(fmaf(dv, u[5], b1.y), 0.f);
    h[6] = fmaxf(fmaf(dv, u[6], b1.z), 0.f);
    h[7] = fmaxf(fmaf(dv, u[7], b1.w), 0.f);

    // second mm (64 -> 8): lane c computes output col c.
    const int base = threadIdx.x & 56;
    float acc = bls[c];
    #pragma unroll
    for (int q = 0; q < 8; ++q) {
        #pragma unroll
        for (int r = 0; r < 8; ++r) {
            float hv = __shfl(h[r], base + q);   // feature q*8+r
            acc = fmaf(hv, Wls[(q * 8 + r) * 8 + c], acc);
        }
    }
    if (node < n) out[(size_t)node * 8 + c] = acc;
}

extern "C" void kernel_launch(void* const* d_in, const int* in_sizes, int n_in,
                              void* d_out, int out_size, void* d_ws, size_t ws_size,
                              hipStream_t stream) {
    const float* x  = (const float*)d_in[0];
    const void*  ei = d_in[1];
    const float* W0 = (const float*)d_in[2];
    const float* b0 = (const float*)d_in[3];
    const float* W1 = (const float*)d_in[4];
    const float* b1 = (const float*)d_in[5];
    const float* W2 = (const float*)d_in[6];
    const float* b2 = (const float*)d_in[7];
    const float* Wl = (const float*)d_in[8];
    const float* bl = (const float*)d_in[9];

    const long long E = in_sizes[1] / 2;                 // 800000
    const int dh = in_sizes[3];                          // 64
    const int din = in_sizes[2] / dh;                    // 64
    const int N = in_sizes[0] / din;                     // 50000
    const int nb = (N + 255) >> 8;                       // 196 buckets

    // Workspace carve (256-aligned): ~39 MB total
    char* ws = (char*)d_ws;
    size_t off = 0;
    auto alloc = [&](size_t bytes) -> char* {
        char* r = ws + off;
        off += (bytes + 255) & ~(size_t)255;
        return r;
    };
    int*   gcur    = (int*)  alloc(1024);
    int2*  meta    = (int2*) alloc((size_t)N * 8);
    int*   perm    = (int*)  alloc((size_t)nb * 256 * 4);       // 200 KB
    int*   pairs   = (int*)  alloc((size_t)nb * CAP * 4);       // 12.8 MB
    int*   csr     = (int*)  alloc((size_t)nb * CAP * 4);       // 12.8 MB
    u16x8* zbA     = (u16x8*)alloc((size_t)(N + 1) * 64 * 2);   // fp16 rows (+zero row)
    u16x8* zbB     = (u16x8*)alloc((size_t)(N + 1) * 64 * 2);

    // --- preprocessing ---
    hipMemsetAsync(gcur, 0, 256 * sizeof(int), stream);
    p3_scatter<<<SC_BLOCKS, TPB, 0, stream>>>(ei, E, gcur, pairs);
    p4_fill<<<nb, TPB, 0, stream>>>(pairs, gcur, x, meta, csr, perm,
                                    (ushort4*)zbA, N);

    // --- 3 layers over ALL perm slots (invalid ids filtered by node<n) ---
    const int gL = nb * 8;                               // (nb*256)/32 = 1568
    layer_mm<<<gL, TPB, 0, stream>>>(zbA, csr, meta, perm, b0, W0, zbB, N);
    layer_mm<<<gL, TPB, 0, stream>>>(zbB, csr, meta, perm, b1, W1, zbA, N);
    layer_final<<<gL, TPB, 0, stream>>>(zbA, csr, meta, perm, b2, W2, Wl, bl,
                                        (float*)d_out, N);
}